// Round 7
// baseline (38775.049 us; speedup 1.0000x reference)
//
#include <hip/hip_runtime.h>

#define S_LEN 4096
#define BATCH 16
#define HID   256     // H == F == 256
#define GATE4 1024    // 4F

typedef __bf16 bf16x8 __attribute__((ext_vector_type(8)));
typedef float  f32x4  __attribute__((ext_vector_type(4)));

union FragU {
    unsigned short u[8];
    bf16x8 v;
    uint4  q;
};

__device__ __forceinline__ unsigned short f2bf(float f) {
    unsigned u = __builtin_bit_cast(unsigned, f);
    u += 0x7fffu + ((u >> 16) & 1u);
    return (unsigned short)(u >> 16);
}
__device__ __forceinline__ float bf2f(unsigned short s) {
    unsigned u = ((unsigned)s) << 16;
    return __builtin_bit_cast(float, u);
}
__device__ __forceinline__ float sigmoid_f(float x) {
    return 1.f / (1.f + __expf(-x));
}
__device__ __forceinline__ float tanh_f(float x) {
    float e = __expf(2.f * x);
    return 1.f - 2.f / (e + 1.f);
}

// ---------------------------------------------------------------------------
// Kernel 0: init. ctrl[8..15]=per-XCD claim counters, ctrl[16]=winner XCD.
// exch (64 KiB) zeroed so poisoned tags can never match a live step tag.
// ---------------------------------------------------------------------------
__global__ void init_ctrl(unsigned int* ctrl, unsigned int* exch4) {
    int t = threadIdx.x;
    if (t < 128) ctrl[t] = (t == 16) ? 0xFFFFFFFFu : 0u;
    for (int i = t; i < 16384; i += 1024) exch4[i] = 0u;
}

// ---------------------------------------------------------------------------
// Kernel 1: xp gemm (unchanged from the proven round-3/6 version)
// ---------------------------------------------------------------------------
__global__ __launch_bounds__(256, 2) void xp_gemm(
    const float* __restrict__ X,
    const float* __restrict__ Wi_fw, const float* __restrict__ b_fw,
    const float* __restrict__ Wi_rv, const float* __restrict__ b_rv,
    unsigned short* __restrict__ xp_fw, unsigned short* __restrict__ xp_rv)
{
    const int dir = blockIdx.z;
    const float* Wi   = dir ? Wi_rv : Wi_fw;
    const float* bias = dir ? b_rv  : b_fw;
    unsigned short* xp = dir ? xp_rv : xp_fw;

    __shared__ unsigned short As[64][40];
    __shared__ unsigned short Bs[64][40];

    const int tid  = threadIdx.x;
    const int lane = tid & 63;
    const int wid  = tid >> 6;
    const int quad = lane >> 4;
    const int l16  = lane & 15;
    const int wm = wid >> 1, wn = wid & 1;

    const int r0 = blockIdx.x * 64;
    const int n0 = blockIdx.y * 64;

    const int ai = tid & 63;
    const int ak = (tid >> 6) * 8;
    const int bk = tid >> 3;
    const int bj = (tid & 7) * 8;

    const int r  = r0 + ai;
    const int t  = r >> 4, bb = r & 15;
    const int t_eff = dir ? (S_LEN - 1 - t) : t;
    const float* Arow = X + ((size_t)bb * S_LEN + t_eff) * HID;

    f32x4 acc[2][2];
    #pragma unroll
    for (int i = 0; i < 2; ++i)
        #pragma unroll
        for (int j = 0; j < 2; ++j) { acc[i][j][0]=0.f; acc[i][j][1]=0.f; acc[i][j][2]=0.f; acc[i][j][3]=0.f; }

    for (int kb = 0; kb < HID / 32; ++kb) {
        {
            const float* p = Arow + kb * 32 + ak;
            float4 v0 = *(const float4*)p;
            float4 v1 = *(const float4*)(p + 4);
            FragU fu;
            fu.u[0]=f2bf(v0.x); fu.u[1]=f2bf(v0.y); fu.u[2]=f2bf(v0.z); fu.u[3]=f2bf(v0.w);
            fu.u[4]=f2bf(v1.x); fu.u[5]=f2bf(v1.y); fu.u[6]=f2bf(v1.z); fu.u[7]=f2bf(v1.w);
            *(uint4*)&As[ai][ak] = fu.q;
        }
        {
            const float* p = Wi + (size_t)(kb * 32 + bk) * GATE4 + n0 + bj;
            float4 v0 = *(const float4*)p;
            float4 v1 = *(const float4*)(p + 4);
            unsigned short tmp[8] = { f2bf(v0.x), f2bf(v0.y), f2bf(v0.z), f2bf(v0.w),
                                      f2bf(v1.x), f2bf(v1.y), f2bf(v1.z), f2bf(v1.w) };
            #pragma unroll
            for (int jj = 0; jj < 8; ++jj) Bs[bj + jj][bk] = tmp[jj];
        }
        __syncthreads();

        bf16x8 a0 = *(const bf16x8*)&As[wm * 32 + l16][quad * 8];
        bf16x8 a1 = *(const bf16x8*)&As[wm * 32 + 16 + l16][quad * 8];
        bf16x8 B0 = *(const bf16x8*)&Bs[wn * 32 + l16][quad * 8];
        bf16x8 B1 = *(const bf16x8*)&Bs[wn * 32 + 16 + l16][quad * 8];
        acc[0][0] = __builtin_amdgcn_mfma_f32_16x16x32_bf16(a0, B0, acc[0][0], 0, 0, 0);
        acc[0][1] = __builtin_amdgcn_mfma_f32_16x16x32_bf16(a0, B1, acc[0][1], 0, 0, 0);
        acc[1][0] = __builtin_amdgcn_mfma_f32_16x16x32_bf16(a1, B0, acc[1][0], 0, 0, 0);
        acc[1][1] = __builtin_amdgcn_mfma_f32_16x16x32_bf16(a1, B1, acc[1][1], 0, 0, 0);
        __syncthreads();
    }

    #pragma unroll
    for (int am = 0; am < 2; ++am)
        #pragma unroll
        for (int bn = 0; bn < 2; ++bn) {
            int ncol = n0 + wn * 32 + bn * 16 + l16;
            float bv = bias[ncol];
            #pragma unroll
            for (int rr = 0; rr < 4; ++rr) {
                int rrow = r0 + wm * 32 + am * 16 + quad * 4 + rr;
                float v = acc[am][bn][rr] + bv;
                xp[(size_t)rrow * GATE4 + ncol] = f2bf(v);
            }
        }
}

// ---------------------------------------------------------------------------
// Kernel 2: recurrence. 64 WGs; election (proven) picks 4 co-XCD WGs with
// roles (dir, half). Exchange protocol identical to r6 (tagged 8B relaxed
// agent atomics, data-is-its-own-flag). NEW: ROTATED loop with SPLIT-K MFMA —
// the own-k half of the next step's MFMA issues BEFORE the poll, so A-frag
// LDS reads + 16 MFMAs + one barrier execute during the partner's MALL
// flight time. sched_barrier(0) pins the MFMA cluster before the poll.
// ---------------------------------------------------------------------------
__global__ __launch_bounds__(512, 2) void lstm_rec(
    const float* __restrict__ Wh_fw, const float* __restrict__ Wh_rv,
    const unsigned short* __restrict__ xp_fw, const unsigned short* __restrict__ xp_rv,
    float* __restrict__ out,            // [B][S][512]
    float* __restrict__ finals,         // c_fw,h_fw,c_rv,h_rv (each 16x256)
    char* __restrict__ exch,            // [dir][parity][half][512 threads][16B]
    unsigned int* __restrict__ ctrl)
{
    const int tid  = threadIdx.x;
    __shared__ int role_s;

    // ---- XCD claim: elect 4 co-XCD workgroups (RMW spin: always coherent) --
    if (tid == 0) {
        unsigned xcc;
        asm volatile("s_getreg_b32 %0, hwreg(HW_REG_XCC_ID)" : "=s"(xcc));
        xcc &= 7u;
        int role = -1;
        unsigned idx = atomicAdd(&ctrl[8u + xcc], 1u);
        if (idx < 4u) {
            if (idx == 3u) atomicCAS(&ctrl[16], 0xFFFFFFFFu, xcc);
            unsigned w;
            while ((w = __hip_atomic_fetch_add(&ctrl[16], 0u, __ATOMIC_RELAXED,
                                               __HIP_MEMORY_SCOPE_AGENT)) == 0xFFFFFFFFu)
                __builtin_amdgcn_s_sleep(2);
            if (w == xcc) role = (int)idx;
        }
        role_s = role;
    }
    __syncthreads();
    const int role = role_s;
    if (role < 0) return;               // uniform per WG

    const int dir  = role >> 1;
    const int half = role & 1;
    const float* Wh = dir ? Wh_rv : Wh_fw;
    const unsigned short* xp = dir ? xp_rv : xp_fw;

    const int lane = tid & 63;
    const int wid  = tid >> 6;          // 0..7
    const int quad = lane >> 4;
    const int l16  = lane & 15;

    const int fbase = half * 128 + wid * 16;   // dir-local f of this wave
    const int floc  = wid * 16 + l16;          // half-local f (0..127)
    const int po    = (1 - half) * 128;        // partner's column base in hbuf
    const int ko    = half * 4;                // own k-tile range (kt offset)
    const int kp    = (1 - half) * 4;          // partner k-tile range

    __shared__ unsigned short hbuf[2][16][264]; // double-buffered full h (bf16)
    // no zero-init needed: rotated loop never reads h before writing it

    // Wh half -> B-fragments (one-time). lane: Wh[kt*32+quad*8+j][g*256+fbase+l16]
    bf16x8 Bfrag[4][8];
    #pragma unroll
    for (int g = 0; g < 4; ++g) {
        int col = g * 256 + fbase + l16;
        #pragma unroll
        for (int kt = 0; kt < 8; ++kt) {
            FragU fu;
            #pragma unroll
            for (int j = 0; j < 8; ++j) {
                int k = kt * 32 + quad * 8 + j;
                fu.u[j] = f2bf(Wh[(size_t)k * GATE4 + col]);
            }
            Bfrag[g][kt] = fu.v;
        }
    }

    float cst[4]  = {0.f, 0.f, 0.f, 0.f};
    float hval[4] = {0.f, 0.f, 0.f, 0.f};

    const size_t lanebase = (size_t)(quad * 4) * GATE4 + fbase + l16;

    // exch slot bases: 8 KiB per (dir,parity,half) block, 16 B per thread
    unsigned long long* exA = (unsigned long long*)(exch
        + (size_t)(((dir * 2 + 0) * 2) + half) * 8192) + (size_t)tid * 2;
    unsigned long long* exB = (unsigned long long*)(exch
        + (size_t)(((dir * 2 + 1) * 2) + half) * 8192) + (size_t)tid * 2;
    const unsigned long long* pdA = (const unsigned long long*)(exch
        + (size_t)(((dir * 2 + 0) * 2) + (1 - half)) * 8192) + (size_t)tid * 2;
    const unsigned long long* pdB = (const unsigned long long*)(exch
        + (size_t)(((dir * 2 + 1) * 2) + (1 - half)) * 8192) + (size_t)tid * 2;

    // xp register sets (even/odd step), refetched 2 ahead
    unsigned short xpA[4][4], xpB[4][4];
    {
        const unsigned short* x0 = xp + lanebase;
        const unsigned short* x1 = xp + (size_t)BATCH * GATE4 + lanebase;
        #pragma unroll
        for (int g = 0; g < 4; ++g)
            #pragma unroll
            for (int rr = 0; rr < 4; ++rr) {
                xpA[g][rr] = x0[(size_t)rr * GATE4 + g * 256];
                xpB[g][rr] = x1[(size_t)rr * GATE4 + g * 256];
            }
    }

    // z-accumulator carried across iterations. s=0: h_{-1}=0 -> z_0 = xp_0.
    f32x4 accg[4];
    #pragma unroll
    for (int g = 0; g < 4; ++g) { accg[g][0]=0.f; accg[g][1]=0.f; accg[g][2]=0.f; accg[g][3]=0.f; }

    auto step = [&](int s, unsigned short (&xpc)[4][4],
                    unsigned long long* exm, const unsigned long long* pdm) {
        const int q = s & 1;
        const bool last = (s == S_LEN - 1);

        // 1. gates: z_s = accg (carried h_{s-1}@Wh) + xp_s
        unsigned short hb[4];
        #pragma unroll
        for (int rr = 0; rr < 4; ++rr) {
            float zi = accg[0][rr] + bf2f(xpc[0][rr]);
            float zf = accg[1][rr] + bf2f(xpc[1][rr]);
            float zg = accg[2][rr] + bf2f(xpc[2][rr]);
            float zo = accg[3][rr] + bf2f(xpc[3][rr]);
            float ig = sigmoid_f(zi);
            float fg = sigmoid_f(zf);
            float gg = tanh_f(zg);
            float og = sigmoid_f(zo);
            float c  = fg * cst[rr] + ig * gg;
            cst[rr]  = c;
            float h  = og * tanh_f(c);
            hval[rr] = h;
            hb[rr]   = f2bf(h);
        }

        if (!last) {
            // 2. publish own half: two tagged 8B relaxed agent atomics
            const unsigned long long tg = (unsigned long long)(unsigned)(s + 1) << 32;
            unsigned long long w0p = tg | (unsigned)hb[0] | ((unsigned)hb[1] << 16);
            unsigned long long w1p = tg | (unsigned)hb[2] | ((unsigned)hb[3] << 16);
            __hip_atomic_store(exm,     w0p, __ATOMIC_RELAXED, __HIP_MEMORY_SCOPE_AGENT);
            __hip_atomic_store(exm + 1, w1p, __ATOMIC_RELAXED, __HIP_MEMORY_SCOPE_AGENT);

            // 3. own half -> hbuf[q]; barrier so all own-half columns visible
            #pragma unroll
            for (int rr = 0; rr < 4; ++rr)
                hbuf[q][quad * 4 + rr][fbase + l16] = hb[rr];
            asm volatile("s_waitcnt lgkmcnt(0)" ::: "memory");
            __builtin_amdgcn_s_barrier();

            // 4. own-k A-frags + own-k MFMA for z_{s+1} — executes during the
            //    partner's MALL flight (MFMA pipe independent of vmcnt waits)
            bf16x8 Afrag[4];
            #pragma unroll
            for (int kt = 0; kt < 4; ++kt)
                Afrag[kt] = *(const bf16x8*)&hbuf[q][l16][(ko + kt) * 32 + quad * 8];
            #pragma unroll
            for (int g = 0; g < 4; ++g) { accg[g][0]=0.f; accg[g][1]=0.f; accg[g][2]=0.f; accg[g][3]=0.f; }
            #pragma unroll
            for (int kt = 0; kt < 4; ++kt) {
                accg[0] = __builtin_amdgcn_mfma_f32_16x16x32_bf16(Afrag[kt], Bfrag[0][ko + kt], accg[0], 0, 0, 0);
                accg[1] = __builtin_amdgcn_mfma_f32_16x16x32_bf16(Afrag[kt], Bfrag[1][ko + kt], accg[1], 0, 0, 0);
                accg[2] = __builtin_amdgcn_mfma_f32_16x16x32_bf16(Afrag[kt], Bfrag[2][ko + kt], accg[2], 0, 0, 0);
                accg[3] = __builtin_amdgcn_mfma_f32_16x16x32_bf16(Afrag[kt], Bfrag[3][ko + kt], accg[3], 0, 0, 0);
            }
            // pin the MFMA cluster before the poll (stop scheduler sinking it)
            __builtin_amdgcn_sched_barrier(0);

            // 5. poll partner's tagged words (relaxed agent atomics, as r6)
            const unsigned tagv = (unsigned)(s + 1);
            unsigned long long w0, w1;
            do {
                w0 = __hip_atomic_load(pdm,     __ATOMIC_RELAXED, __HIP_MEMORY_SCOPE_AGENT);
                w1 = __hip_atomic_load(pdm + 1, __ATOMIC_RELAXED, __HIP_MEMORY_SCOPE_AGENT);
            } while ((unsigned)(w0 >> 32) != tagv || (unsigned)(w1 >> 32) != tagv);

            // 6. xp refetch 2 ahead (full step of flight time before next poll)
            if (s + 2 < S_LEN) {
                const unsigned short* xr = xp + (size_t)(s + 2) * (BATCH * GATE4) + lanebase;
                #pragma unroll
                for (int g = 0; g < 4; ++g)
                    #pragma unroll
                    for (int rr = 0; rr < 4; ++rr)
                        xpc[g][rr] = xr[(size_t)rr * GATE4 + g * 256];
            }

            // 7. partner half -> hbuf[q]
            hbuf[q][quad * 4 + 0][po + floc] = (unsigned short)(w0);
            hbuf[q][quad * 4 + 1][po + floc] = (unsigned short)(w0 >> 16);
            hbuf[q][quad * 4 + 2][po + floc] = (unsigned short)(w1);
            hbuf[q][quad * 4 + 3][po + floc] = (unsigned short)(w1 >> 16);

            // 8. out stores for h_s (fire & forget)
            {
                int t_orig = dir ? (S_LEN - 1 - s) : s;
                float* ob = out + (size_t)t_orig * 512 + dir * 256 + fbase + l16;
                #pragma unroll
                for (int rr = 0; rr < 4; ++rr)
                    ob[(size_t)(quad * 4 + rr) * S_LEN * 512] = hval[rr];
            }

            asm volatile("s_waitcnt lgkmcnt(0)" ::: "memory");
            __builtin_amdgcn_s_barrier();

            // 9. partner-k A-frags + MFMA (completes z_{s+1})
            bf16x8 Pfrag[4];
            #pragma unroll
            for (int kt = 0; kt < 4; ++kt)
                Pfrag[kt] = *(const bf16x8*)&hbuf[q][l16][(kp + kt) * 32 + quad * 8];
            #pragma unroll
            for (int kt = 0; kt < 4; ++kt) {
                accg[0] = __builtin_amdgcn_mfma_f32_16x16x32_bf16(Pfrag[kt], Bfrag[0][kp + kt], accg[0], 0, 0, 0);
                accg[1] = __builtin_amdgcn_mfma_f32_16x16x32_bf16(Pfrag[kt], Bfrag[1][kp + kt], accg[1], 0, 0, 0);
                accg[2] = __builtin_amdgcn_mfma_f32_16x16x32_bf16(Pfrag[kt], Bfrag[2][kp + kt], accg[2], 0, 0, 0);
                accg[3] = __builtin_amdgcn_mfma_f32_16x16x32_bf16(Pfrag[kt], Bfrag[3][kp + kt], accg[3], 0, 0, 0);
            }
        } else {
            // last step: just the out stores
            int t_orig = dir ? (S_LEN - 1 - s) : s;
            float* ob = out + (size_t)t_orig * 512 + dir * 256 + fbase + l16;
            #pragma unroll
            for (int rr = 0; rr < 4; ++rr)
                ob[(size_t)(quad * 4 + rr) * S_LEN * 512] = hval[rr];
        }
    };

    for (int s2 = 0; s2 < S_LEN; s2 += 2) {
        step(s2,     xpA, exA, pdA);
        step(s2 + 1, xpB, exB, pdB);
    }

    // final states: c then h, fw block then rv block
    {
        float* cdst = finals + (dir ? 8192 : 0);
        float* hdst = cdst + 4096;
        #pragma unroll
        for (int rr = 0; rr < 4; ++rr) {
            int m = quad * 4 + rr;
            int f = fbase + l16;
            cdst[m * 256 + f] = cst[rr];
            hdst[m * 256 + f] = hval[rr];
        }
    }
}

// ---------------------------------------------------------------------------
extern "C" void kernel_launch(void* const* d_in, const int* in_sizes, int n_in,
                              void* d_out, int out_size, void* d_ws, size_t ws_size,
                              hipStream_t stream)
{
    const float* X     = (const float*)d_in[0];
    const float* Wi_fw = (const float*)d_in[1];
    const float* Wh_fw = (const float*)d_in[2];
    const float* b_fw  = (const float*)d_in[3];
    const float* Wi_rv = (const float*)d_in[4];
    const float* Wh_rv = (const float*)d_in[5];
    const float* b_rv  = (const float*)d_in[6];

    float* out    = (float*)d_out;
    float* finals = out + (size_t)BATCH * S_LEN * 512;

    char* ws = (char*)d_ws;
    unsigned short* xp_fw = (unsigned short*)ws;                          // 128 MiB
    unsigned short* xp_rv = (unsigned short*)(ws + 134217728ull);         // 128 MiB
    char*           exch  = ws + 268435456ull;                            // 64 KiB
    unsigned int*   ctrl  = (unsigned int*)(ws + 268435456ull + 65536ull);// 512 B

    init_ctrl<<<1, 1024, 0, stream>>>(ctrl, (unsigned int*)exch);

    dim3 g(65536 / 64, 1024 / 64, 2);
    xp_gemm<<<g, 256, 0, stream>>>(X, Wi_fw, b_fw, Wi_rv, b_rv, xp_fw, xp_rv);

    lstm_rec<<<64, 512, 0, stream>>>(Wh_fw, Wh_rv, xp_fw, xp_rv, out, finals, exch, ctrl);
}

// Round 8
// 12661.007 us; speedup vs baseline: 3.0626x; 3.0626x over previous
//
#include <hip/hip_runtime.h>

#define S_LEN 4096
#define BATCH 16
#define HID   256     // H == F == 256
#define GATE4 1024    // 4F

typedef __bf16 bf16x8 __attribute__((ext_vector_type(8)));
typedef float  f32x4  __attribute__((ext_vector_type(4)));

union FragU {
    unsigned short u[8];
    bf16x8 v;
    uint4  q;
};

__device__ __forceinline__ unsigned short f2bf(float f) {
    unsigned u = __builtin_bit_cast(unsigned, f);
    u += 0x7fffu + ((u >> 16) & 1u);
    return (unsigned short)(u >> 16);
}
__device__ __forceinline__ float bf2f(unsigned short s) {
    unsigned u = ((unsigned)s) << 16;
    return __builtin_bit_cast(float, u);
}
__device__ __forceinline__ float sigmoid_f(float x) {
    return 1.f / (1.f + __expf(-x));
}
__device__ __forceinline__ float tanh_f(float x) {
    float e = __expf(2.f * x);
    return 1.f - 2.f / (e + 1.f);
}

// ---------------------------------------------------------------------------
// Kernel 0: init. ctrl[8..15]=per-XCD claim counters, ctrl[16]=winner XCD.
// exch (64 KiB) zeroed so poisoned tags can never match a live step tag.
// ---------------------------------------------------------------------------
__global__ void init_ctrl(unsigned int* ctrl, unsigned int* exch4) {
    int t = threadIdx.x;
    if (t < 128) ctrl[t] = (t == 16) ? 0xFFFFFFFFu : 0u;
    for (int i = t; i < 16384; i += 1024) exch4[i] = 0u;
}

// ---------------------------------------------------------------------------
// Kernel 1: xp gemm (unchanged from the proven round-3/6 version)
// ---------------------------------------------------------------------------
__global__ __launch_bounds__(256, 2) void xp_gemm(
    const float* __restrict__ X,
    const float* __restrict__ Wi_fw, const float* __restrict__ b_fw,
    const float* __restrict__ Wi_rv, const float* __restrict__ b_rv,
    unsigned short* __restrict__ xp_fw, unsigned short* __restrict__ xp_rv)
{
    const int dir = blockIdx.z;
    const float* Wi   = dir ? Wi_rv : Wi_fw;
    const float* bias = dir ? b_rv  : b_fw;
    unsigned short* xp = dir ? xp_rv : xp_fw;

    __shared__ unsigned short As[64][40];
    __shared__ unsigned short Bs[64][40];

    const int tid  = threadIdx.x;
    const int lane = tid & 63;
    const int wid  = tid >> 6;
    const int quad = lane >> 4;
    const int l16  = lane & 15;
    const int wm = wid >> 1, wn = wid & 1;

    const int r0 = blockIdx.x * 64;
    const int n0 = blockIdx.y * 64;

    const int ai = tid & 63;
    const int ak = (tid >> 6) * 8;
    const int bk = tid >> 3;
    const int bj = (tid & 7) * 8;

    const int r  = r0 + ai;
    const int t  = r >> 4, bb = r & 15;
    const int t_eff = dir ? (S_LEN - 1 - t) : t;
    const float* Arow = X + ((size_t)bb * S_LEN + t_eff) * HID;

    f32x4 acc[2][2];
    #pragma unroll
    for (int i = 0; i < 2; ++i)
        #pragma unroll
        for (int j = 0; j < 2; ++j) { acc[i][j][0]=0.f; acc[i][j][1]=0.f; acc[i][j][2]=0.f; acc[i][j][3]=0.f; }

    for (int kb = 0; kb < HID / 32; ++kb) {
        {
            const float* p = Arow + kb * 32 + ak;
            float4 v0 = *(const float4*)p;
            float4 v1 = *(const float4*)(p + 4);
            FragU fu;
            fu.u[0]=f2bf(v0.x); fu.u[1]=f2bf(v0.y); fu.u[2]=f2bf(v0.z); fu.u[3]=f2bf(v0.w);
            fu.u[4]=f2bf(v1.x); fu.u[5]=f2bf(v1.y); fu.u[6]=f2bf(v1.z); fu.u[7]=f2bf(v1.w);
            *(uint4*)&As[ai][ak] = fu.q;
        }
        {
            const float* p = Wi + (size_t)(kb * 32 + bk) * GATE4 + n0 + bj;
            float4 v0 = *(const float4*)p;
            float4 v1 = *(const float4*)(p + 4);
            unsigned short tmp[8] = { f2bf(v0.x), f2bf(v0.y), f2bf(v0.z), f2bf(v0.w),
                                      f2bf(v1.x), f2bf(v1.y), f2bf(v1.z), f2bf(v1.w) };
            #pragma unroll
            for (int jj = 0; jj < 8; ++jj) Bs[bj + jj][bk] = tmp[jj];
        }
        __syncthreads();

        bf16x8 a0 = *(const bf16x8*)&As[wm * 32 + l16][quad * 8];
        bf16x8 a1 = *(const bf16x8*)&As[wm * 32 + 16 + l16][quad * 8];
        bf16x8 B0 = *(const bf16x8*)&Bs[wn * 32 + l16][quad * 8];
        bf16x8 B1 = *(const bf16x8*)&Bs[wn * 32 + 16 + l16][quad * 8];
        acc[0][0] = __builtin_amdgcn_mfma_f32_16x16x32_bf16(a0, B0, acc[0][0], 0, 0, 0);
        acc[0][1] = __builtin_amdgcn_mfma_f32_16x16x32_bf16(a0, B1, acc[0][1], 0, 0, 0);
        acc[1][0] = __builtin_amdgcn_mfma_f32_16x16x32_bf16(a1, B0, acc[1][0], 0, 0, 0);
        acc[1][1] = __builtin_amdgcn_mfma_f32_16x16x32_bf16(a1, B1, acc[1][1], 0, 0, 0);
        __syncthreads();
    }

    #pragma unroll
    for (int am = 0; am < 2; ++am)
        #pragma unroll
        for (int bn = 0; bn < 2; ++bn) {
            int ncol = n0 + wn * 32 + bn * 16 + l16;
            float bv = bias[ncol];
            #pragma unroll
            for (int rr = 0; rr < 4; ++rr) {
                int rrow = r0 + wm * 32 + am * 16 + quad * 4 + rr;
                float v = acc[am][bn][rr] + bv;
                xp[(size_t)rrow * GATE4 + ncol] = f2bf(v);
            }
        }
}

// ---------------------------------------------------------------------------
// Kernel 2: recurrence. 64 WGs; election picks 4 co-XCD WGs, roles (dir,half).
// Exchange protocol identical to r6 (tagged 8B relaxed agent atomics).
// Rotated loop with SPLIT-K MFMA: own-k half of next step's MFMA issues
// BEFORE the poll (overlapping the partner's MALL flight). FIX vs r7:
// fragment arrays split by role (BfO/BfP) so ALL register indices are
// compile-time constants — r7's Bfrag[g][ko+kt] runtime index sent 128
// VGPRs of Wh to scratch (VGPR_Count 84, 3.3x regression, rule #20).
// ---------------------------------------------------------------------------
__global__ __launch_bounds__(512, 2) void lstm_rec(
    const float* __restrict__ Wh_fw, const float* __restrict__ Wh_rv,
    const unsigned short* __restrict__ xp_fw, const unsigned short* __restrict__ xp_rv,
    float* __restrict__ out,            // [B][S][512]
    float* __restrict__ finals,         // c_fw,h_fw,c_rv,h_rv (each 16x256)
    char* __restrict__ exch,            // [dir][parity][half][512 threads][16B]
    unsigned int* __restrict__ ctrl)
{
    const int tid  = threadIdx.x;
    __shared__ int role_s;

    // ---- XCD claim: elect 4 co-XCD workgroups (RMW spin: always coherent) --
    if (tid == 0) {
        unsigned xcc;
        asm volatile("s_getreg_b32 %0, hwreg(HW_REG_XCC_ID)" : "=s"(xcc));
        xcc &= 7u;
        int role = -1;
        unsigned idx = atomicAdd(&ctrl[8u + xcc], 1u);
        if (idx < 4u) {
            if (idx == 3u) atomicCAS(&ctrl[16], 0xFFFFFFFFu, xcc);
            unsigned w;
            while ((w = __hip_atomic_fetch_add(&ctrl[16], 0u, __ATOMIC_RELAXED,
                                               __HIP_MEMORY_SCOPE_AGENT)) == 0xFFFFFFFFu)
                __builtin_amdgcn_s_sleep(2);
            if (w == xcc) role = (int)idx;
        }
        role_s = role;
    }
    __syncthreads();
    const int role = role_s;
    if (role < 0) return;               // uniform per WG

    const int dir  = role >> 1;
    const int half = role & 1;
    const float* Wh = dir ? Wh_rv : Wh_fw;
    const unsigned short* xp = dir ? xp_rv : xp_fw;

    const int lane = tid & 63;
    const int wid  = tid >> 6;          // 0..7
    const int quad = lane >> 4;
    const int l16  = lane & 15;

    const int fbase = half * 128 + wid * 16;   // dir-local f of this wave
    const int floc  = wid * 16 + l16;          // half-local f (0..127)
    const int po    = (1 - half) * 128;        // partner's column base in hbuf
    const int ko    = half * 4;                // own k-tile offset (LDS addr only)
    const int kp    = (1 - half) * 4;          // partner k-tile offset (LDS addr only)

    __shared__ unsigned short hbuf[2][16][264]; // double-buffered full h (bf16)
    // no zero-init needed: rotated loop always writes h before reading it

    // Wh half -> B-fragments, SPLIT BY ROLE so register indices are literal:
    // BfO[g][kt] = k-rows [half*128 + kt*32 ...), BfP[g][kt] = partner k-rows.
    bf16x8 BfO[4][4], BfP[4][4];
    #pragma unroll
    for (int g = 0; g < 4; ++g) {
        const int col = g * 256 + fbase + l16;
        #pragma unroll
        for (int kt = 0; kt < 4; ++kt) {
            FragU fo, fp;
            #pragma unroll
            for (int j = 0; j < 8; ++j) {
                int k_own = (ko + kt) * 32 + quad * 8 + j;
                int k_par = (kp + kt) * 32 + quad * 8 + j;
                fo.u[j] = f2bf(Wh[(size_t)k_own * GATE4 + col]);
                fp.u[j] = f2bf(Wh[(size_t)k_par * GATE4 + col]);
            }
            BfO[g][kt] = fo.v;
            BfP[g][kt] = fp.v;
        }
    }

    float cst[4]  = {0.f, 0.f, 0.f, 0.f};
    float hval[4] = {0.f, 0.f, 0.f, 0.f};

    const size_t lanebase = (size_t)(quad * 4) * GATE4 + fbase + l16;

    // exch slot bases: 8 KiB per (dir,parity,half) block, 16 B per thread
    unsigned long long* exA = (unsigned long long*)(exch
        + (size_t)(((dir * 2 + 0) * 2) + half) * 8192) + (size_t)tid * 2;
    unsigned long long* exB = (unsigned long long*)(exch
        + (size_t)(((dir * 2 + 1) * 2) + half) * 8192) + (size_t)tid * 2;
    const unsigned long long* pdA = (const unsigned long long*)(exch
        + (size_t)(((dir * 2 + 0) * 2) + (1 - half)) * 8192) + (size_t)tid * 2;
    const unsigned long long* pdB = (const unsigned long long*)(exch
        + (size_t)(((dir * 2 + 1) * 2) + (1 - half)) * 8192) + (size_t)tid * 2;

    // xp register sets (even/odd step), refetched 2 ahead
    unsigned short xpA[4][4], xpB[4][4];
    {
        const unsigned short* x0 = xp + lanebase;
        const unsigned short* x1 = xp + (size_t)BATCH * GATE4 + lanebase;
        #pragma unroll
        for (int g = 0; g < 4; ++g)
            #pragma unroll
            for (int rr = 0; rr < 4; ++rr) {
                xpA[g][rr] = x0[(size_t)rr * GATE4 + g * 256];
                xpB[g][rr] = x1[(size_t)rr * GATE4 + g * 256];
            }
    }

    // z-accumulator carried across iterations. s=0: h_{-1}=0 -> z_0 = xp_0.
    f32x4 accg[4];
    #pragma unroll
    for (int g = 0; g < 4; ++g) { accg[g][0]=0.f; accg[g][1]=0.f; accg[g][2]=0.f; accg[g][3]=0.f; }

    auto step = [&](int s, unsigned short (&xpc)[4][4],
                    unsigned long long* exm, const unsigned long long* pdm) {
        const int q = s & 1;
        const bool last = (s == S_LEN - 1);

        // 1. gates: z_s = accg (carried h_{s-1}@Wh) + xp_s
        unsigned short hb[4];
        #pragma unroll
        for (int rr = 0; rr < 4; ++rr) {
            float zi = accg[0][rr] + bf2f(xpc[0][rr]);
            float zf = accg[1][rr] + bf2f(xpc[1][rr]);
            float zg = accg[2][rr] + bf2f(xpc[2][rr]);
            float zo = accg[3][rr] + bf2f(xpc[3][rr]);
            float ig = sigmoid_f(zi);
            float fg = sigmoid_f(zf);
            float gg = tanh_f(zg);
            float og = sigmoid_f(zo);
            float c  = fg * cst[rr] + ig * gg;
            cst[rr]  = c;
            float h  = og * tanh_f(c);
            hval[rr] = h;
            hb[rr]   = f2bf(h);
        }

        if (!last) {
            // 2. publish own half: two tagged 8B relaxed agent atomics
            const unsigned long long tg = (unsigned long long)(unsigned)(s + 1) << 32;
            unsigned long long w0p = tg | (unsigned)hb[0] | ((unsigned)hb[1] << 16);
            unsigned long long w1p = tg | (unsigned)hb[2] | ((unsigned)hb[3] << 16);
            __hip_atomic_store(exm,     w0p, __ATOMIC_RELAXED, __HIP_MEMORY_SCOPE_AGENT);
            __hip_atomic_store(exm + 1, w1p, __ATOMIC_RELAXED, __HIP_MEMORY_SCOPE_AGENT);

            // 3. own half -> hbuf[q]; barrier so all own-half columns visible
            #pragma unroll
            for (int rr = 0; rr < 4; ++rr)
                hbuf[q][quad * 4 + rr][fbase + l16] = hb[rr];
            asm volatile("s_waitcnt lgkmcnt(0)" ::: "memory");
            __builtin_amdgcn_s_barrier();

            // 4. own-k A-frags + own-k MFMA for z_{s+1} — executes during the
            //    partner's MALL flight (MFMA pipe independent of vmcnt waits).
            //    Register indices all literal; ko only in LDS address math.
            bf16x8 Afrag[4];
            #pragma unroll
            for (int kt = 0; kt < 4; ++kt)
                Afrag[kt] = *(const bf16x8*)&hbuf[q][l16][(ko + kt) * 32 + quad * 8];
            #pragma unroll
            for (int g = 0; g < 4; ++g) { accg[g][0]=0.f; accg[g][1]=0.f; accg[g][2]=0.f; accg[g][3]=0.f; }
            #pragma unroll
            for (int kt = 0; kt < 4; ++kt) {
                accg[0] = __builtin_amdgcn_mfma_f32_16x16x32_bf16(Afrag[kt], BfO[0][kt], accg[0], 0, 0, 0);
                accg[1] = __builtin_amdgcn_mfma_f32_16x16x32_bf16(Afrag[kt], BfO[1][kt], accg[1], 0, 0, 0);
                accg[2] = __builtin_amdgcn_mfma_f32_16x16x32_bf16(Afrag[kt], BfO[2][kt], accg[2], 0, 0, 0);
                accg[3] = __builtin_amdgcn_mfma_f32_16x16x32_bf16(Afrag[kt], BfO[3][kt], accg[3], 0, 0, 0);
            }
            // pin the MFMA cluster before the poll (stop scheduler sinking it)
            __builtin_amdgcn_sched_barrier(0);

            // 5. poll partner's tagged words (relaxed agent atomics, as r6)
            const unsigned tagv = (unsigned)(s + 1);
            unsigned long long w0, w1;
            do {
                w0 = __hip_atomic_load(pdm,     __ATOMIC_RELAXED, __HIP_MEMORY_SCOPE_AGENT);
                w1 = __hip_atomic_load(pdm + 1, __ATOMIC_RELAXED, __HIP_MEMORY_SCOPE_AGENT);
            } while ((unsigned)(w0 >> 32) != tagv || (unsigned)(w1 >> 32) != tagv);

            // 6. xp refetch 2 ahead (full step of flight time before next use)
            if (s + 2 < S_LEN) {
                const unsigned short* xr = xp + (size_t)(s + 2) * (BATCH * GATE4) + lanebase;
                #pragma unroll
                for (int g = 0; g < 4; ++g)
                    #pragma unroll
                    for (int rr = 0; rr < 4; ++rr)
                        xpc[g][rr] = xr[(size_t)rr * GATE4 + g * 256];
            }

            // 7. partner half -> hbuf[q]
            hbuf[q][quad * 4 + 0][po + floc] = (unsigned short)(w0);
            hbuf[q][quad * 4 + 1][po + floc] = (unsigned short)(w0 >> 16);
            hbuf[q][quad * 4 + 2][po + floc] = (unsigned short)(w1);
            hbuf[q][quad * 4 + 3][po + floc] = (unsigned short)(w1 >> 16);

            // 8. out stores for h_s (fire & forget)
            {
                int t_orig = dir ? (S_LEN - 1 - s) : s;
                float* ob = out + (size_t)t_orig * 512 + dir * 256 + fbase + l16;
                #pragma unroll
                for (int rr = 0; rr < 4; ++rr)
                    ob[(size_t)(quad * 4 + rr) * S_LEN * 512] = hval[rr];
            }

            asm volatile("s_waitcnt lgkmcnt(0)" ::: "memory");
            __builtin_amdgcn_s_barrier();

            // 9. partner-k A-frags + MFMA (completes z_{s+1})
            bf16x8 Pfrag[4];
            #pragma unroll
            for (int kt = 0; kt < 4; ++kt)
                Pfrag[kt] = *(const bf16x8*)&hbuf[q][l16][(kp + kt) * 32 + quad * 8];
            #pragma unroll
            for (int kt = 0; kt < 4; ++kt) {
                accg[0] = __builtin_amdgcn_mfma_f32_16x16x32_bf16(Pfrag[kt], BfP[0][kt], accg[0], 0, 0, 0);
                accg[1] = __builtin_amdgcn_mfma_f32_16x16x32_bf16(Pfrag[kt], BfP[1][kt], accg[1], 0, 0, 0);
                accg[2] = __builtin_amdgcn_mfma_f32_16x16x32_bf16(Pfrag[kt], BfP[2][kt], accg[2], 0, 0, 0);
                accg[3] = __builtin_amdgcn_mfma_f32_16x16x32_bf16(Pfrag[kt], BfP[3][kt], accg[3], 0, 0, 0);
            }
        } else {
            // last step: just the out stores
            int t_orig = dir ? (S_LEN - 1 - s) : s;
            float* ob = out + (size_t)t_orig * 512 + dir * 256 + fbase + l16;
            #pragma unroll
            for (int rr = 0; rr < 4; ++rr)
                ob[(size_t)(quad * 4 + rr) * S_LEN * 512] = hval[rr];
        }
    };

    for (int s2 = 0; s2 < S_LEN; s2 += 2) {
        step(s2,     xpA, exA, pdA);
        step(s2 + 1, xpB, exB, pdB);
    }

    // final states: c then h, fw block then rv block
    {
        float* cdst = finals + (dir ? 8192 : 0);
        float* hdst = cdst + 4096;
        #pragma unroll
        for (int rr = 0; rr < 4; ++rr) {
            int m = quad * 4 + rr;
            int f = fbase + l16;
            cdst[m * 256 + f] = cst[rr];
            hdst[m * 256 + f] = hval[rr];
        }
    }
}

// ---------------------------------------------------------------------------
extern "C" void kernel_launch(void* const* d_in, const int* in_sizes, int n_in,
                              void* d_out, int out_size, void* d_ws, size_t ws_size,
                              hipStream_t stream)
{
    const float* X     = (const float*)d_in[0];
    const float* Wi_fw = (const float*)d_in[1];
    const float* Wh_fw = (const float*)d_in[2];
    const float* b_fw  = (const float*)d_in[3];
    const float* Wi_rv = (const float*)d_in[4];
    const float* Wh_rv = (const float*)d_in[5];
    const float* b_rv  = (const float*)d_in[6];

    float* out    = (float*)d_out;
    float* finals = out + (size_t)BATCH * S_LEN * 512;

    char* ws = (char*)d_ws;
    unsigned short* xp_fw = (unsigned short*)ws;                          // 128 MiB
    unsigned short* xp_rv = (unsigned short*)(ws + 134217728ull);         // 128 MiB
    char*           exch  = ws + 268435456ull;                            // 64 KiB
    unsigned int*   ctrl  = (unsigned int*)(ws + 268435456ull + 65536ull);// 512 B

    init_ctrl<<<1, 1024, 0, stream>>>(ctrl, (unsigned int*)exch);

    dim3 g(65536 / 64, 1024 / 64, 2);
    xp_gemm<<<g, 256, 0, stream>>>(X, Wi_fw, b_fw, Wi_rv, b_rv, xp_fw, xp_rv);

    lstm_rec<<<64, 512, 0, stream>>>(Wh_fw, Wh_rv, xp_fw, xp_rv, out, finals, exch, ctrl);
}